// Round 2
// baseline (1320.877 us; speedup 1.0000x reference)
//
#include <hip/hip_runtime.h>
#include <hip/hip_bf16.h>

// Sinkhorn via diagonal-scaling factorization:
//   M = exp(x)+eps;  repeat 100x: r = 1/(M c); c = 1/(M^T r);  y = diag(r) M diag(c)
// Mh (bf16) + MhT (bf16 transpose) are staged in d_out (8 MiB each = exactly out bytes).
// Persistent kernel: 256 WGs (<= #CUs -> co-resident), hand-rolled device barriers
// using agent-scope atomics only (no acquire fence -> no L2 invalidate -> M stays in L2).

#define BATCH   16
#define NDIM    512
#define NNEL    (NDIM * NDIM)
#define ITERS   100
#define EPS_K   0.001f
#define WPB     16      // workgroups per batch
#define RPW     32      // rows (or cols) per workgroup
#define THREADS 512
#define CSTRIDE 64      // counter padding in ints (256 B)

__device__ __forceinline__ unsigned short f2bf(float f) {
  unsigned int u = __float_as_uint(f);
  u += 0x7fffu + ((u >> 16) & 1u);          // round-to-nearest-even
  return (unsigned short)(u >> 16);
}

// ---------------- Kernel 1: M = exp(x)+eps -> bf16 Mh and MhT, zero counters ---
__global__ __launch_bounds__(256) void prep_kernel(const float* __restrict__ x,
                                                   unsigned short* __restrict__ mh,
                                                   unsigned short* __restrict__ mht,
                                                   int* __restrict__ counters) {
  __shared__ float t[64][65];
  const int bid = blockIdx.x;
  if (bid == 0 && threadIdx.x < 32) counters[(int)threadIdx.x * CSTRIDE] = 0;
  const int b    = bid >> 6;          // 64 tiles of 64x64 per batch
  const int tile = bid & 63;
  const int tr   = (tile >> 3) << 6;
  const int tc   = (tile & 7) << 6;
  const int lx   = threadIdx.x & 63;
  const int ty   = threadIdx.x >> 6;  // 0..3
  const size_t base = (size_t)b * NNEL;
#pragma unroll
  for (int k = 0; k < 16; ++k) {
    int row = (k << 2) + ty;
    float v = expf(x[base + (size_t)(tr + row) * NDIM + tc + lx]) + EPS_K;
    mh[base + (size_t)(tr + row) * NDIM + tc + lx] = f2bf(v);
    t[row][lx] = v;
  }
  __syncthreads();
#pragma unroll
  for (int k = 0; k < 16; ++k) {
    int row = (k << 2) + ty;  // row of transposed tile = col of M
    mht[base + (size_t)(tc + row) * NDIM + tr + lx] = f2bf(t[lx][row]);
  }
}

// ---------------- cross-WG barrier (monotonic counter, no acquire fence) ------
__device__ __forceinline__ void wg_barrier(int* cnt, int target) {
  __syncthreads();  // all waves drained before arrive
  if (threadIdx.x == 0) {
    __hip_atomic_fetch_add(cnt, 1, __ATOMIC_RELEASE, __HIP_MEMORY_SCOPE_AGENT);
    int guard = 0;
    while (__hip_atomic_load(cnt, __ATOMIC_RELAXED, __HIP_MEMORY_SCOPE_AGENT) < target) {
      __builtin_amdgcn_s_sleep(2);
      if (++guard > (1 << 22)) break;  // safety valve; never taken when co-resident
    }
    asm volatile("" ::: "memory");
  }
  __syncthreads();
}

// one row (512 bf16) dotted with cc[8] held per-lane; full sum in all lanes
__device__ __forceinline__ float dot_row(const unsigned short* mrow, int lane,
                                         const float* cc) {
  uint4 v = *(const uint4*)(mrow + lane * 8);  // cols lane*8 .. lane*8+7, coalesced
  float p;
  p  = __uint_as_float(v.x << 16)         * cc[0];
  p += __uint_as_float(v.x & 0xffff0000u) * cc[1];
  p += __uint_as_float(v.y << 16)         * cc[2];
  p += __uint_as_float(v.y & 0xffff0000u) * cc[3];
  p += __uint_as_float(v.z << 16)         * cc[4];
  p += __uint_as_float(v.z & 0xffff0000u) * cc[5];
  p += __uint_as_float(v.w << 16)         * cc[6];
  p += __uint_as_float(v.w & 0xffff0000u) * cc[7];
#pragma unroll
  for (int o = 32; o > 0; o >>= 1) p += __shfl_xor(p, o, 64);
  return p;
}

// ---------------- Kernel 2: persistent Sinkhorn + epilogue --------------------
__global__ __launch_bounds__(THREADS, 4) void sinkhorn_kernel(
    const unsigned short* mh, const unsigned short* mht, float* yout,
    float* r_g, float* c_g, int* counters) {
  __shared__ alignas(16) float vec[NDIM];              // broadcast of r or c
  __shared__ float rown[RPW];                          // this WG's final r values
  __shared__ alignas(16) unsigned short stage[RPW * NDIM];  // epilogue Mh rows
  const int wg   = blockIdx.x;
  const int b    = wg >> 4;
  const int sub  = wg & 15;
  const int i0   = sub * RPW;
  const int tid  = threadIdx.x;
  const int w    = tid >> 6;
  const int lane = tid & 63;
  int* bcnt = counters + b * CSTRIDE;
  int* gcnt = counters + 16 * CSTRIDE;
  const size_t mbase = (size_t)b * NNEL;
  float* rg = r_g + b * NDIM;
  float* cg = c_g + b * NDIM;
  int bar = 0;
  float cc[8];
#pragma unroll
  for (int k = 0; k < 8; ++k) cc[k] = 1.0f;  // c0 = ones

#pragma unroll 1
  for (int t = 0; t < ITERS; ++t) {
    // ---- row step: r = 1/(Mh c) ----
    if (t > 0) {
      vec[tid] = __hip_atomic_load(&cg[tid], __ATOMIC_RELAXED, __HIP_MEMORY_SCOPE_AGENT);
      __syncthreads();
      float4 a = ((const float4*)vec)[lane * 2];
      float4 d = ((const float4*)vec)[lane * 2 + 1];
      cc[0] = a.x; cc[1] = a.y; cc[2] = a.z; cc[3] = a.w;
      cc[4] = d.x; cc[5] = d.y; cc[6] = d.z; cc[7] = d.w;
    }
#pragma unroll
    for (int rr = 0; rr < 4; ++rr) {
      int rel = (w << 2) + rr;
      int row = i0 + rel;
      float s = dot_row(mh + mbase + (size_t)row * NDIM, lane, cc);
      if (lane == 0) {
        float rv = 1.0f / s;
        rown[rel] = rv;
        __hip_atomic_store(&rg[row], rv, __ATOMIC_RELAXED, __HIP_MEMORY_SCOPE_AGENT);
      }
    }
    ++bar; wg_barrier(bcnt, WPB * bar);

    // ---- col step: c = 1/(MhT r) ----
    vec[tid] = __hip_atomic_load(&rg[tid], __ATOMIC_RELAXED, __HIP_MEMORY_SCOPE_AGENT);
    __syncthreads();
    {
      float4 a = ((const float4*)vec)[lane * 2];
      float4 d = ((const float4*)vec)[lane * 2 + 1];
      cc[0] = a.x; cc[1] = a.y; cc[2] = a.z; cc[3] = a.w;
      cc[4] = d.x; cc[5] = d.y; cc[6] = d.z; cc[7] = d.w;
    }
#pragma unroll
    for (int rr = 0; rr < 4; ++rr) {
      int rel = (w << 2) + rr;
      int col = i0 + rel;
      float s = dot_row(mht + mbase + (size_t)col * NDIM, lane, cc);
      if (lane == 0) {
        __hip_atomic_store(&cg[col], 1.0f / s, __ATOMIC_RELAXED, __HIP_MEMORY_SCOPE_AGENT);
      }
    }
    ++bar; wg_barrier(bcnt, WPB * bar);
  }

  // ---- epilogue: y = diag(r) M diag(c); y overwrites Mh/MhT in d_out ----
  vec[tid] = __hip_atomic_load(&cg[tid], __ATOMIC_RELAXED, __HIP_MEMORY_SCOPE_AGENT);
  const uint4* src = (const uint4*)(mh + mbase + (size_t)i0 * NDIM);
  uint4* dst = (uint4*)stage;
#pragma unroll
  for (int k = 0; k < 4; ++k) dst[tid + k * THREADS] = src[tid + k * THREADS];
  // all 256 WGs must finish READING Mh before anyone WRITES y over it
  wg_barrier(gcnt, 256);
#pragma unroll
  for (int rr = 0; rr < 4; ++rr) {
    int rel = (w << 2) + rr;
    int row = i0 + rel;
    float rv = rown[rel];
    uint2 ma = *(const uint2*)(stage + rel * NDIM + lane * 4);
    uint2 mb = *(const uint2*)(stage + rel * NDIM + 256 + lane * 4);
    float4 ca = ((const float4*)vec)[lane];
    float4 cb = ((const float4*)(vec + 256))[lane];
    float4 oa, ob;
    oa.x = rv * __uint_as_float(ma.x << 16)         * ca.x;
    oa.y = rv * __uint_as_float(ma.x & 0xffff0000u) * ca.y;
    oa.z = rv * __uint_as_float(ma.y << 16)         * ca.z;
    oa.w = rv * __uint_as_float(ma.y & 0xffff0000u) * ca.w;
    ob.x = rv * __uint_as_float(mb.x << 16)         * cb.x;
    ob.y = rv * __uint_as_float(mb.x & 0xffff0000u) * cb.y;
    ob.z = rv * __uint_as_float(mb.y << 16)         * cb.z;
    ob.w = rv * __uint_as_float(mb.y & 0xffff0000u) * cb.w;
    *(float4*)(yout + mbase + (size_t)row * NDIM + lane * 4) = oa;
    *(float4*)(yout + mbase + (size_t)row * NDIM + 256 + lane * 4) = ob;
  }
}

extern "C" void kernel_launch(void* const* d_in, const int* in_sizes, int n_in,
                              void* d_out, int out_size, void* d_ws, size_t ws_size,
                              hipStream_t stream) {
  const float* x = (const float*)d_in[0];
  float* yout = (float*)d_out;
  unsigned short* mh  = (unsigned short*)d_out;            // 8 MiB bf16 M
  unsigned short* mht = mh + (size_t)BATCH * NNEL;         // 8 MiB bf16 M^T
  float* r_g = (float*)d_ws;                               // 32 KiB
  float* c_g = r_g + BATCH * NDIM;                         // 32 KiB
  int* counters = (int*)(c_g + BATCH * NDIM);              // ~8 KiB padded

  hipLaunchKernelGGL(prep_kernel, dim3(BATCH * 64), dim3(256), 0, stream,
                     x, mh, mht, counters);
  hipLaunchKernelGGL(sinkhorn_kernel, dim3(BATCH * WPB), dim3(THREADS), 0, stream,
                     mh, mht, yout, r_g, c_g, counters);
}